// Round 4
// baseline (254.902 us; speedup 1.0000x reference)
//
#include <hip/hip_runtime.h>
#include <hip/hip_bf16.h>

#define NN    500000
#define DIN   256
#define DATT  128
#define NG    4096
#define MT    64
#define NBLK  7813        // ceil(NN/64)
#define CPX   977         // tiles per XCD chunk; 8*977 = 7816
#define GRID  7816

typedef __attribute__((ext_vector_type(8))) short short8;
typedef __attribute__((ext_vector_type(4))) float f32x4;

// pack two f32 -> two bf16 (round-half-up; <=1ulp off RNE only at exact ties)
__device__ __forceinline__ unsigned int pack2bf(float a, float b) {
    unsigned int ua = __float_as_uint(a) + 0x8000u;
    unsigned int ub = __float_as_uint(b) + 0x8000u;
    return __builtin_amdgcn_perm(ub, ua, 0x07060302);  // [ub.b3,ub.b2,ua.b3,ua.b2]
}

// tanh(x) = 1 - 2/(1+e^{2x})
__device__ __forceinline__ float tanh_fast(float v) {
    float e = __expf(2.f * v);
    return 1.f - 2.f * __builtin_amdgcn_rcpf(e + 1.f);
}

// one-time: W1 [256][128] fp32 -> W1t [128][256] bf16 (transposed) in d_ws
__global__ void prep_w1t(const float* __restrict__ W1, unsigned short* __restrict__ W1t) {
    int c = blockIdx.x;      // 0..127
    int k = threadIdx.x;     // 0..255
    unsigned int u = __float_as_uint(W1[k * DATT + c]) + 0x8000u;
    W1t[c * DIN + k] = (unsigned short)(u >> 16);
}

// Fused: h = tanh(x@W1+b1); attn = h@W2+b2; out[batch[n]] += attn[n]*x[n]
// 256 threads = 4 waves. xs bf16 [64][256], XOR-swizzled (byte ^= (row&7)<<4).
// GEMM computes h^T via mfma(A=W1^T-frag(from L2), B=x^T-frag(xs rows)) so the
// DATT reduction is per-lane VALU + 2 shfl (not 64 DS shuffles).
// Wave w covers h-cols [32w,32w+32); pooling: wave w owns nodes 16w..16w+15,
// lane covers dims 4l..4l+3, attn/bid broadcast via v_readlane (0 DS).
__global__ __launch_bounds__(256, 3)
void attnpool_kernel(const float* __restrict__ x,
                     const int* __restrict__ batch,
                     const unsigned short* __restrict__ W1t,
                     const float* __restrict__ b1,
                     const float* __restrict__ W2,
                     const float* __restrict__ b2,
                     float* __restrict__ out)
{
    __shared__ unsigned short xs[MT * DIN];   // 32 KB swizzled
    __shared__ float part[4][MT];
    __shared__ float attn_s[MT];
    __shared__ int   bid_s[MT];

    const int bidx = blockIdx.x;
    const int t = (bidx & 7) * CPX + (bidx >> 3);   // XCD-chunked swizzle
    if (t >= NBLK) return;

    const int tid = threadIdx.x;
    const int w   = tid >> 6;        // wave 0..3
    const int l   = tid & 63;
    const int lr  = l & 15;
    const int lg  = l >> 4;
    const long long n0 = (long long)t * MT;

    // ---- stage x tile: fp32 global -> bf16 swizzled LDS
    const float4* xg = (const float4*)x;
    #pragma unroll
    for (int i = 0; i < 16; ++i) {
        int j  = tid + i * 256;
        int r  = j >> 6;
        int c4 = j & 63;
        long long n = n0 + r;
        float4 v = make_float4(0.f, 0.f, 0.f, 0.f);
        if (n < NN) v = xg[n * 64 + c4];
        unsigned int w0 = pack2bf(v.x, v.y);
        unsigned int w1 = pack2bf(v.z, v.w);
        int byte = r * 512 + ((c4 * 8) ^ ((r & 7) << 4));
        *reinterpret_cast<uint2*>(reinterpret_cast<char*>(xs) + byte) = make_uint2(w0, w1);
    }
    if (tid < MT) {
        long long n = n0 + tid;
        int g = -1;
        if (n < NN) {
            g = batch[n];
            if (g < 0 || g >= NG) g = -1;
        }
        bid_s[tid] = g;
    }
    __syncthreads();

    // ---- GEMM h^T: wave w computes h-cols [32w, 32w+32) for all 64 nodes.
    // acc[rt2][ct]: D-tile rows (h-cols) [32w+16rt2, +16) x node-cols [16ct, +16)
    // A-frag (W1^T): lane supplies A[row=lr][k=32kc+8lg+i] = W1t[32w+16rt2+lr][...]
    // B-frag (x^T):  lane supplies B[k=32kc+8lg+i][col=lr], col=node 16ct+lr
    f32x4 acc[2][4];
    #pragma unroll
    for (int r2 = 0; r2 < 2; ++r2)
        #pragma unroll
        for (int ct = 0; ct < 4; ++ct)
            acc[r2][ct] = (f32x4){0.f, 0.f, 0.f, 0.f};

    const unsigned short* Arow = W1t + (32 * w + lr) * DIN;
    #pragma unroll
    for (int kc = 0; kc < 8; ++kc) {
        int ko = 32 * kc + 8 * lg;
        short8 a0 = *reinterpret_cast<const short8*>(Arow + ko);
        short8 a1 = *reinterpret_cast<const short8*>(Arow + 16 * DIN + ko);
        short8 bfr[4];
        #pragma unroll
        for (int ct = 0; ct < 4; ++ct) {
            int row = 16 * ct + lr;
            int byte = row * 512 + ((ko * 2) ^ ((row & 7) << 4));
            bfr[ct] = *reinterpret_cast<const short8*>(reinterpret_cast<const char*>(xs) + byte);
        }
        #pragma unroll
        for (int ct = 0; ct < 4; ++ct) {
            acc[0][ct] = __builtin_amdgcn_mfma_f32_16x16x32_bf16(a0, bfr[ct], acc[0][ct], 0, 0, 0);
            acc[1][ct] = __builtin_amdgcn_mfma_f32_16x16x32_bf16(a1, bfr[ct], acc[1][ct], 0, 0, 0);
        }
    }

    // ---- attn: lane holds h[node=16ct+lr][c=32w+16rt2+4lg+j]
    float4 b1v[2], w2v[2];
    #pragma unroll
    for (int r2 = 0; r2 < 2; ++r2) {
        int c0 = 32 * w + 16 * r2 + 4 * lg;
        b1v[r2] = *reinterpret_cast<const float4*>(&b1[c0]);
        w2v[r2] = *reinterpret_cast<const float4*>(&W2[c0]);
    }
    #pragma unroll
    for (int ct = 0; ct < 4; ++ct) {
        float p = 0.f;
        #pragma unroll
        for (int r2 = 0; r2 < 2; ++r2) {
            p += tanh_fast(acc[r2][ct][0] + b1v[r2].x) * w2v[r2].x;
            p += tanh_fast(acc[r2][ct][1] + b1v[r2].y) * w2v[r2].y;
            p += tanh_fast(acc[r2][ct][2] + b1v[r2].z) * w2v[r2].z;
            p += tanh_fast(acc[r2][ct][3] + b1v[r2].w) * w2v[r2].w;
        }
        p += __shfl_xor(p, 16, 64);
        p += __shfl_xor(p, 32, 64);
        if (lg == 0) part[w][16 * ct + lr] = p;
    }
    __syncthreads();

    if (tid < MT)
        attn_s[tid] = b2[0] + part[0][tid] + part[1][tid] + part[2][tid] + part[3][tid];
    __syncthreads();

    // ---- pooling: wave w -> nodes [16w, 16w+16); lane -> dims 4l..4l+3
    float av = attn_s[16 * w + lr];     // lanes lr,lr+16,.. broadcast
    int   bv = bid_s[16 * w + lr];
    float a0 = 0.f, a1 = 0.f, a2 = 0.f, a3 = 0.f;
    int gcur = __builtin_amdgcn_readlane(bv, 0);
    #pragma unroll
    for (int n = 0; n < 16; ++n) {
        int   g = __builtin_amdgcn_readlane(bv, n);
        float a = __int_as_float(__builtin_amdgcn_readlane(__float_as_int(av), n));
        if (g != gcur) {
            if (gcur >= 0) {
                float* o = &out[(long long)gcur * DIN + 4 * l];
                atomicAdd(o + 0, a0); atomicAdd(o + 1, a1);
                atomicAdd(o + 2, a2); atomicAdd(o + 3, a3);
            }
            a0 = a1 = a2 = a3 = 0.f;
            gcur = g;
        }
        int row = 16 * w + n;
        int byte = row * 512 + ((8 * l) ^ ((row & 7) << 4));
        uint2 xv = *reinterpret_cast<const uint2*>(reinterpret_cast<const char*>(xs) + byte);
        a0 = fmaf(a, __uint_as_float(xv.x << 16), a0);
        a1 = fmaf(a, __uint_as_float(xv.x & 0xffff0000u), a1);
        a2 = fmaf(a, __uint_as_float(xv.y << 16), a2);
        a3 = fmaf(a, __uint_as_float(xv.y & 0xffff0000u), a3);
    }
    if (gcur >= 0) {
        float* o = &out[(long long)gcur * DIN + 4 * l];
        atomicAdd(o + 0, a0); atomicAdd(o + 1, a1);
        atomicAdd(o + 2, a2); atomicAdd(o + 3, a3);
    }
}

extern "C" void kernel_launch(void* const* d_in, const int* in_sizes, int n_in,
                              void* d_out, int out_size, void* d_ws, size_t ws_size,
                              hipStream_t stream) {
    const float* x     = (const float*)d_in[0];
    const int*   batch = (const int*)d_in[1];     // int32 (JAX x64 disabled)
    const float* W1 = (const float*)d_in[3];
    const float* b1 = (const float*)d_in[4];
    const float* W2 = (const float*)d_in[5];
    const float* b2 = (const float*)d_in[6];
    float* out = (float*)d_out;
    unsigned short* W1t = (unsigned short*)d_ws;   // 64 KB

    hipMemsetAsync(out, 0, (size_t)NG * DIN * sizeof(float), stream);
    prep_w1t<<<DATT, DIN, 0, stream>>>(W1, W1t);
    attnpool_kernel<<<GRID, 256, 0, stream>>>(x, batch, W1t, b1, W2, b2, out);
}

// Round 8
// 223.142 us; speedup vs baseline: 1.1423x; 1.1423x over previous
//
#include <hip/hip_runtime.h>
#include <hip/hip_bf16.h>

#define NN    500000
#define DIN   256
#define DATT  128
#define NG    4096
#define MT    64
#define NBLK  7813        // ceil(NN/64)
#define CPX   977         // tiles per XCD chunk; 8*977 = 7816
#define GRID  7816

typedef __attribute__((ext_vector_type(8))) short short8;
typedef __attribute__((ext_vector_type(4))) float f32x4;

// pack two f32 -> two bf16 (round-half-up)
__device__ __forceinline__ unsigned int pack2bf(float a, float b) {
    unsigned int ua = __float_as_uint(a) + 0x8000u;
    unsigned int ub = __float_as_uint(b) + 0x8000u;
    return __builtin_amdgcn_perm(ub, ua, 0x07060302);  // [ub.b3,ub.b2,ua.b3,ua.b2]
}

// tanh(x) = 1 - 2/(1+e^{2x})
__device__ __forceinline__ float tanh_fast(float v) {
    float e = __expf(2.f * v);
    return 1.f - 2.f * __builtin_amdgcn_rcpf(e + 1.f);
}

// one-time: W1 [256][128] fp32 -> W1t [128][256] bf16 (transposed) in d_ws
__global__ void prep_w1t(const float* __restrict__ W1, unsigned short* __restrict__ W1t) {
    int c = blockIdx.x;      // 0..127
    int k = threadIdx.x;     // 0..255
    unsigned int u = __float_as_uint(W1[k * DATT + c]) + 0x8000u;
    W1t[c * DIN + k] = (unsigned short)(u >> 16);
}

// Fused: h = tanh(x@W1+b1); attn = h@W2+b2; out[batch[n]] += attn[n]*x[n]
// 256 threads = 4 waves. xs bf16 [64][256] XOR-swizzled (byte ^= (row&7)<<4).
// GEMM computes h^T = mfma(A=W1^T-frag, B=x^T-frag): DATT reduction is 8 regs
// + 2 shfl. A-frags (W1^T, 32 h-cols/wave) preloaded into 64 VGPRs at kernel
// top -> their L2 latency hides under x staging; ZERO global loads in k-loop.
// Pooling: wave w owns nodes 16w..16w+15, lane covers dims 4l..4l+3,
// attn/bid broadcast via v_readlane; atomics only at sorted-graph boundaries.
__global__ __launch_bounds__(256, 3)
void attnpool_kernel(const float* __restrict__ x,
                     const int* __restrict__ batch,
                     const unsigned short* __restrict__ W1t,
                     const float* __restrict__ b1,
                     const float* __restrict__ W2,
                     const float* __restrict__ b2,
                     float* __restrict__ out)
{
    __shared__ unsigned short xs[MT * DIN];   // 32 KB swizzled
    __shared__ float part[4][MT];
    __shared__ int   bid_s[MT];

    const int bidx = blockIdx.x;
    const int t = (bidx & 7) * CPX + (bidx >> 3);   // XCD-chunked swizzle
    if (t >= NBLK) return;

    const int tid = threadIdx.x;
    const int w   = tid >> 6;        // wave 0..3
    const int l   = tid & 63;
    const int lr  = l & 15;
    const int lg  = l >> 4;
    const long long n0 = (long long)t * MT;

    // ---- preload A-frags (W1^T rows 32w..32w+31), issued before staging:
    // afr[kc]   : rows 32w+lr,    k = 32kc+8lg..+8   (r2=0)
    // afr[8+kc] : rows 32w+16+lr, k = 32kc+8lg..+8   (r2=1)
    short8 afr[16];
    {
        const unsigned short* A0 = W1t + (32 * w + lr) * DIN;
        #pragma unroll
        for (int kc = 0; kc < 8; ++kc) {
            afr[kc]     = *reinterpret_cast<const short8*>(A0 + 32 * kc + 8 * lg);
            afr[8 + kc] = *reinterpret_cast<const short8*>(A0 + 16 * DIN + 32 * kc + 8 * lg);
        }
    }

    // ---- stage x tile: fp32 global -> bf16 swizzled LDS
    const float4* xg = (const float4*)x;
    #pragma unroll
    for (int i = 0; i < 16; ++i) {
        int j  = tid + i * 256;
        int r  = j >> 6;
        int c4 = j & 63;
        long long n = n0 + r;
        float4 v = make_float4(0.f, 0.f, 0.f, 0.f);
        if (n < NN) v = xg[n * 64 + c4];
        unsigned int w0 = pack2bf(v.x, v.y);
        unsigned int w1 = pack2bf(v.z, v.w);
        int byte = r * 512 + ((c4 * 8) ^ ((r & 7) << 4));
        *reinterpret_cast<uint2*>(reinterpret_cast<char*>(xs) + byte) = make_uint2(w0, w1);
    }
    if (tid < MT) {
        long long n = n0 + tid;
        int g = -1;
        if (n < NN) {
            g = batch[n];
            if (g < 0 || g >= NG) g = -1;
        }
        bid_s[tid] = g;
    }
    __syncthreads();

    // ---- GEMM h^T: acc[r2][ct] = D rows (h-cols) [32w+16r2,+16) x nodes [16ct,+16)
    f32x4 acc[2][4];
    #pragma unroll
    for (int r2 = 0; r2 < 2; ++r2)
        #pragma unroll
        for (int ct = 0; ct < 4; ++ct)
            acc[r2][ct] = (f32x4){0.f, 0.f, 0.f, 0.f};

    #pragma unroll
    for (int kc = 0; kc < 8; ++kc) {
        int ko = 32 * kc + 8 * lg;
        short8 bfr[4];
        #pragma unroll
        for (int ct = 0; ct < 4; ++ct) {
            int row = 16 * ct + lr;
            int byte = row * 512 + ((ko * 2) ^ ((row & 7) << 4));
            bfr[ct] = *reinterpret_cast<const short8*>(reinterpret_cast<const char*>(xs) + byte);
        }
        #pragma unroll
        for (int ct = 0; ct < 4; ++ct) {
            acc[0][ct] = __builtin_amdgcn_mfma_f32_16x16x32_bf16(afr[kc],     bfr[ct], acc[0][ct], 0, 0, 0);
            acc[1][ct] = __builtin_amdgcn_mfma_f32_16x16x32_bf16(afr[8 + kc], bfr[ct], acc[1][ct], 0, 0, 0);
        }
    }

    // ---- attn partials: lane holds h[node=16ct+lr][col=32w+16r2+4lg+j]
    float4 b1v[2], w2v[2];
    #pragma unroll
    for (int r2 = 0; r2 < 2; ++r2) {
        int c0 = 32 * w + 16 * r2 + 4 * lg;
        b1v[r2] = *reinterpret_cast<const float4*>(&b1[c0]);
        w2v[r2] = *reinterpret_cast<const float4*>(&W2[c0]);
    }
    #pragma unroll
    for (int ct = 0; ct < 4; ++ct) {
        float p = 0.f;
        #pragma unroll
        for (int r2 = 0; r2 < 2; ++r2) {
            p += tanh_fast(acc[r2][ct][0] + b1v[r2].x) * w2v[r2].x;
            p += tanh_fast(acc[r2][ct][1] + b1v[r2].y) * w2v[r2].y;
            p += tanh_fast(acc[r2][ct][2] + b1v[r2].z) * w2v[r2].z;
            p += tanh_fast(acc[r2][ct][3] + b1v[r2].w) * w2v[r2].w;
        }
        p += __shfl_xor(p, 16, 64);
        p += __shfl_xor(p, 32, 64);
        if (lg == 0) part[w][16 * ct + lr] = p;
    }
    __syncthreads();

    // ---- pooling: wave w -> nodes [16w,16w+16); lane -> dims 4l..4l+3
    const int nd = 16 * w + lr;
    float av = b2[0] + part[0][nd] + part[1][nd] + part[2][nd] + part[3][nd];
    int   bv = bid_s[nd];
    float a0 = 0.f, a1 = 0.f, a2 = 0.f, a3 = 0.f;
    int gcur = __builtin_amdgcn_readlane(bv, 0);
    #pragma unroll
    for (int n = 0; n < 16; ++n) {
        int   g = __builtin_amdgcn_readlane(bv, n);
        float a = __int_as_float(__builtin_amdgcn_readlane(__float_as_int(av), n));
        if (g != gcur) {
            if (gcur >= 0) {
                float* o = &out[(long long)gcur * DIN + 4 * l];
                atomicAdd(o + 0, a0); atomicAdd(o + 1, a1);
                atomicAdd(o + 2, a2); atomicAdd(o + 3, a3);
            }
            a0 = a1 = a2 = a3 = 0.f;
            gcur = g;
        }
        int row = 16 * w + n;
        int byte = row * 512 + ((8 * l) ^ ((row & 7) << 4));
        uint2 xv = *reinterpret_cast<const uint2*>(reinterpret_cast<const char*>(xs) + byte);
        a0 = fmaf(a, __uint_as_float(xv.x << 16), a0);
        a1 = fmaf(a, __uint_as_float(xv.x & 0xffff0000u), a1);
        a2 = fmaf(a, __uint_as_float(xv.y << 16), a2);
        a3 = fmaf(a, __uint_as_float(xv.y & 0xffff0000u), a3);
    }
    if (gcur >= 0) {
        float* o = &out[(long long)gcur * DIN + 4 * l];
        atomicAdd(o + 0, a0); atomicAdd(o + 1, a1);
        atomicAdd(o + 2, a2); atomicAdd(o + 3, a3);
    }
}

extern "C" void kernel_launch(void* const* d_in, const int* in_sizes, int n_in,
                              void* d_out, int out_size, void* d_ws, size_t ws_size,
                              hipStream_t stream) {
    const float* x     = (const float*)d_in[0];
    const int*   batch = (const int*)d_in[1];     // int32 (JAX x64 disabled)
    const float* W1 = (const float*)d_in[3];
    const float* b1 = (const float*)d_in[4];
    const float* W2 = (const float*)d_in[5];
    const float* b2 = (const float*)d_in[6];
    float* out = (float*)d_out;
    unsigned short* W1t = (unsigned short*)d_ws;   // 64 KB

    hipMemsetAsync(out, 0, (size_t)NG * DIN * sizeof(float), stream);
    prep_w1t<<<DATT, DIN, 0, stream>>>(W1, W1t);
    attnpool_kernel<<<GRID, 256, 0, stream>>>(x, batch, W1t, b1, W2, b2, out);
}